// Round 1
// baseline (1097.393 us; speedup 1.0000x reference)
//
#include <hip/hip_runtime.h>

typedef unsigned short ushort_t;
typedef short bf16x8 __attribute__((ext_vector_type(8)));
typedef float f32x4 __attribute__((ext_vector_type(4)));

#define H 1900
#define FH 7600      // 4*H
#define BATCH 8192
#define KP 1952      // padded K stride: 1900 m | 20 pad | 10 inputs | 22 pad (mult of 32)
#define NP_A 1920    // padded N for gemmA (m columns)
#define NB 7680      // padded row count of whxT
#define BK 32
#define KITERS (KP / BK)   // 61

// ---- ws layout (bytes) ----
static const size_t OFF_SWX  = 0;          // 7600 f32
static const size_t OFF_SWH  = 32768;      // 7600 f32
static const size_t OFF_SWMX = 65536;      // 1900 f32
static const size_t OFF_SWMH = 73728;      // 1900 f32
static const size_t OFF_WMXN = 81920;      // 10*1920 f32 (pre-scaled wmx_n)
static const size_t OFF_PART = 163840;     // partial colsums: 8*(7600+7600+1900+1900) f32
static const size_t OFF_HBF  = 786432;                   // h_prev bf16 [8192][1952]
static const size_t OFF_MEXT = OFF_HBF + 31981568;       // m_ext bf16 [8192][1952]
static const size_t OFF_WMHT = OFF_MEXT + 31981568;      // wmh_n^T bf16 [1920][1952]
static const size_t OFF_WHXT = OFF_WMHT + 7495680;       // [wh_n|wx_n]^T perm bf16 [7680][1952]
// end = OFF_WHXT + 29982720 ≈ 97.5 MB

// partial-sum sub-offsets (in floats, within OFF_PART)
#define PW_X  0
#define PW_H  60800
#define PW_MX 121600
#define PW_MH 136800

__device__ __forceinline__ ushort_t f2bf(float x) {
  unsigned u = __float_as_uint(x);
  return (ushort_t)((u + 0x7fffu + ((u >> 16) & 1u)) >> 16);
}

// ---------------- scales: per-column l2-norm partials, then gain*rsqrt ----------------
__global__ void colsum_partial_kernel(const float* __restrict__ wx, const float* __restrict__ wh,
                                      const float* __restrict__ wmx, const float* __restrict__ wmh,
                                      float* __restrict__ parts) {
  int c = blockIdx.x * 256 + threadIdx.x;
  int y = blockIdx.y, p = blockIdx.z;
  const float* W; int K, N; float* out;
  if (y == 0)      { W = wx;  K = 10;   N = FH; out = parts + PW_X  + (size_t)p * FH; }
  else if (y == 1) { W = wh;  K = 1900; N = FH; out = parts + PW_H  + (size_t)p * FH; }
  else if (y == 2) { W = wmx; K = 10;   N = H;  out = parts + PW_MX + (size_t)p * H;  }
  else             { W = wmh; K = 1900; N = H;  out = parts + PW_MH + (size_t)p * H;  }
  if (c >= N) return;
  int rp = (K + 7) / 8;
  int r0 = p * rp, r1 = r0 + rp; if (r1 > K) r1 = K;
  float s = 0.f;
  for (int r = r0; r < r1; ++r) { float v = W[(size_t)r * N + c]; s += v * v; }
  out[c] = s;
}

__global__ void scales_final_kernel(const float* __restrict__ parts,
                                    const float* __restrict__ gx, const float* __restrict__ gh,
                                    const float* __restrict__ gmx, const float* __restrict__ gmh,
                                    float* __restrict__ s_wx, float* __restrict__ s_wh,
                                    float* __restrict__ s_wmx, float* __restrict__ s_wmh) {
  int c = blockIdx.x * 256 + threadIdx.x;
  int y = blockIdx.y;
  const float* pp; int N; const float* g; float* out;
  if (y == 0)      { pp = parts + PW_X;  N = FH; g = gx;  out = s_wx;  }
  else if (y == 1) { pp = parts + PW_H;  N = FH; g = gh;  out = s_wh;  }
  else if (y == 2) { pp = parts + PW_MX; N = H;  g = gmx; out = s_wmx; }
  else             { pp = parts + PW_MH; N = H;  g = gmh; out = s_wmh; }
  if (c >= N) return;
  float s = 0.f;
  for (int p = 0; p < 8; ++p) s += pp[(size_t)p * N + c];
  out[c] = g[c] * rsqrtf(fmaxf(s, 1e-12f));
}

// ---------------- conversions ----------------
__global__ void cvt_h_kernel(const float* __restrict__ h_prev, ushort_t* __restrict__ hbf) {
  size_t idx = (size_t)blockIdx.x * 256 + threadIdx.x;   // < 8192*1952
  int row = (int)(idx / KP), col = (int)(idx % KP);
  float v = (col < H) ? h_prev[(size_t)row * H + col] : 0.f;
  hbf[idx] = f2bf(v);
}

__global__ void wmxn_kernel(const float* __restrict__ wmx, const float* __restrict__ s_wmx,
                            float* __restrict__ wmxn) {
  int idx = blockIdx.x * 256 + threadIdx.x;  // < 19200
  int i = idx / NP_A, j = idx - i * NP_A;
  wmxn[idx] = (j < H) ? wmx[i * H + j] * s_wmx[j] : 0.f;
}

// wmh [1900][1900] -> wmhT [1920][1952] bf16, transposed, pre-scaled
__global__ void wmhT_kernel(const float* __restrict__ wmh, const float* __restrict__ s_wmh,
                            ushort_t* __restrict__ wmhT) {
  __shared__ float tile[32][33];
  int n0 = blockIdx.x * 32, k0 = blockIdx.y * 32;
  int tx = threadIdx.x & 31, ty = threadIdx.x >> 5;   // ty 0..7
#pragma unroll
  for (int it = 0; it < 4; ++it) {
    int k = k0 + ty + it * 8, n = n0 + tx;
    float v = (k < H && n < H) ? wmh[(size_t)k * H + n] : 0.f;
    tile[ty + it * 8][tx] = v;   // tile[k_local][n_local]
  }
  __syncthreads();
#pragma unroll
  for (int it = 0; it < 4; ++it) {
    int n = n0 + ty + it * 8, k = k0 + tx;
    float v = tile[tx][ty + it * 8];
    float s = (n < H) ? s_wmh[n] : 0.f;
    wmhT[(size_t)n * KP + k] = f2bf(v * s);
  }
}

// wh [1900][7600] + wx [10][7600] -> whxT [7680][1952]: row n=4j+g <- col c=g*1900+j,
// k<1900: wh_n ; 1920<=k<1930: wx_n ; else 0. Pre-scaled.
__global__ void whxT_kernel(const float* __restrict__ wh, const float* __restrict__ wx,
                            const float* __restrict__ s_wh, const float* __restrict__ s_wx,
                            ushort_t* __restrict__ whxT) {
  __shared__ float tile[32][33];
  int c0 = blockIdx.x * 32, k0 = blockIdx.y * 32;
  int tx = threadIdx.x & 31, ty = threadIdx.x >> 5;
#pragma unroll
  for (int it = 0; it < 4; ++it) {
    int k = k0 + ty + it * 8, c = c0 + tx;
    float v = 0.f;
    if (c < FH) {
      if (k < H) v = wh[(size_t)k * FH + c] * s_wh[c];
      else if (k >= NP_A && k < NP_A + 10) v = wx[(size_t)(k - NP_A) * FH + c] * s_wx[c];
    }
    tile[ty + it * 8][tx] = v;   // tile[k_local][c_local]
  }
  __syncthreads();
#pragma unroll
  for (int it = 0; it < 4; ++it) {
    int c = c0 + ty + it * 8, k = k0 + tx;
    if (c < FH) {
      int g = c / H; int j = c - g * H; int n = 4 * j + g;
      whxT[(size_t)n * KP + k] = f2bf(tile[tx][ty + it * 8]);
    }
  }
}

__global__ void mext_tail_kernel(const float* __restrict__ inputs, ushort_t* __restrict__ m_ext) {
  int idx = blockIdx.x * 256 + threadIdx.x;   // < 8192*32
  int row = idx >> 5, c = idx & 31;
  float v = (c < 10) ? inputs[(size_t)row * 10 + c] : 0.f;
  m_ext[(size_t)row * KP + NP_A + c] = f2bf(v);
}

__global__ void whxT_tail_kernel(ushort_t* __restrict__ whxT) {
  int idx = blockIdx.x * 256 + threadIdx.x;   // < 80*1952
  whxT[(size_t)FH * KP + idx] = 0;
}

// ---------------- GEMM core: 128x128 tile, BK=32, NT, 16x16x32 bf16 MFMA ----------------
__device__ __forceinline__ void gemm_tile(const ushort_t* __restrict__ Ag,
                                          const ushort_t* __restrict__ Bg,
                                          int m0, int n0,
                                          ushort_t* As, ushort_t* Bs,
                                          f32x4 acc[4][4]) {
  const int tid = threadIdx.x;
  const int lane = tid & 63;
  const int quad = lane >> 4;
  const int lo = lane & 15;
  const int wave = tid >> 6;
  const int wm = (wave & 1) << 6;
  const int wn = (wave >> 1) << 6;
  const int sm = tid >> 1;            // staging row 0..127
  const int sh = (tid & 1) << 4;      // k-offset 0 or 16 elements
  const ushort_t* Ap = Ag + (size_t)(m0 + sm) * KP + sh;
  const ushort_t* Bp = Bg + (size_t)(n0 + sm) * KP + sh;
  for (int kt = 0; kt < KITERS; ++kt) {
    uint4 a0 = *(const uint4*)(Ap);
    uint4 a1 = *(const uint4*)(Ap + 8);
    uint4 b0 = *(const uint4*)(Bp);
    uint4 b1 = *(const uint4*)(Bp + 8);
    __syncthreads();   // previous iter's LDS reads complete
    *(uint4*)(As + sm * BK + sh)     = a0;
    *(uint4*)(As + sm * BK + sh + 8) = a1;
    *(uint4*)(Bs + sm * BK + sh)     = b0;
    *(uint4*)(Bs + sm * BK + sh + 8) = b1;
    __syncthreads();
    bf16x8 af[4], bfv[4];
#pragma unroll
    for (int mf = 0; mf < 4; ++mf)
      af[mf] = *(const bf16x8*)(As + (wm + mf * 16 + lo) * BK + quad * 8);
#pragma unroll
    for (int nf = 0; nf < 4; ++nf)
      bfv[nf] = *(const bf16x8*)(Bs + (wn + nf * 16 + lo) * BK + quad * 8);
#pragma unroll
    for (int mf = 0; mf < 4; ++mf)
#pragma unroll
      for (int nf = 0; nf < 4; ++nf)
        acc[mf][nf] = __builtin_amdgcn_mfma_f32_16x16x32_bf16(af[mf], bfv[nf], acc[mf][nf], 0, 0, 0);
    Ap += BK; Bp += BK;
  }
}

// GEMM-A: P = h_prev_bf @ wmh_n^T ; epilogue m = (inputs·wmx_n) * P -> m_ext bf16
__global__ void __launch_bounds__(256) gemmA_kernel(const ushort_t* __restrict__ hbf,
                                                    const ushort_t* __restrict__ wmhT,
                                                    const float* __restrict__ inputs,
                                                    const float* __restrict__ wmxn,
                                                    ushort_t* __restrict__ m_ext) {
  __shared__ __align__(16) char smem[16384];
  ushort_t* As = (ushort_t*)smem;
  ushort_t* Bs = (ushort_t*)(smem + 8192);
  f32x4 acc[4][4];
  f32x4 zv = {0.f, 0.f, 0.f, 0.f};
#pragma unroll
  for (int a = 0; a < 4; ++a)
#pragma unroll
    for (int bq = 0; bq < 4; ++bq) acc[a][bq] = zv;
  int m0 = blockIdx.x * 128, n0 = blockIdx.y * 128;
  gemm_tile(hbf, wmhT, m0, n0, As, Bs, acc);
  __syncthreads();
  float* inL  = (float*)smem;            // [128][10]
  float* wmxL = (float*)(smem + 5120);   // [10][128]
  for (int t = threadIdx.x; t < 1280; t += 256) {
    int r = t / 10, i = t - r * 10;
    inL[t] = inputs[(size_t)(m0 + r) * 10 + i];
  }
  for (int t = threadIdx.x; t < 1280; t += 256) {
    int i = t >> 7, c = t & 127;
    wmxL[t] = wmxn[i * NP_A + n0 + c];
  }
  __syncthreads();
  const int lane = threadIdx.x & 63, quad = lane >> 4, lo = lane & 15;
  const int wave = threadIdx.x >> 6, wm = (wave & 1) << 6, wn = (wave >> 1) << 6;
#pragma unroll
  for (int mf = 0; mf < 4; ++mf)
#pragma unroll
    for (int r = 0; r < 4; ++r) {
      int rl = wm + mf * 16 + quad * 4 + r;
      float inrow[10];
#pragma unroll
      for (int i = 0; i < 10; ++i) inrow[i] = inL[rl * 10 + i];
#pragma unroll
      for (int nf = 0; nf < 4; ++nf) {
        int cl = wn + nf * 16 + lo;
        float mx = 0.f;
#pragma unroll
        for (int i = 0; i < 10; ++i) mx += inrow[i] * wmxL[i * 128 + cl];
        float mv = acc[mf][nf][r] * mx;
        m_ext[(size_t)(m0 + rl) * KP + (n0 + cl)] = f2bf(mv);
      }
    }
}

// GEMM-B: z = m_ext @ whxT^T (+bias) ; epilogue: gates via shfl butterfly -> h, c
__global__ void __launch_bounds__(256) gemmB_kernel(const ushort_t* __restrict__ mext,
                                                    const ushort_t* __restrict__ whxT,
                                                    const float* __restrict__ bvec,
                                                    const float* __restrict__ c_prev,
                                                    float* __restrict__ hout,
                                                    float* __restrict__ cout) {
  __shared__ __align__(16) char smem[16384];
  ushort_t* As = (ushort_t*)smem;
  ushort_t* Bs = (ushort_t*)(smem + 8192);
  f32x4 acc[4][4];
  f32x4 zv = {0.f, 0.f, 0.f, 0.f};
#pragma unroll
  for (int a = 0; a < 4; ++a)
#pragma unroll
    for (int bq = 0; bq < 4; ++bq) acc[a][bq] = zv;
  int m0 = blockIdx.x * 128, n0 = blockIdx.y * 128;
  gemm_tile(mext, whxT, m0, n0, As, Bs, acc);
  const int lane = threadIdx.x & 63, quad = lane >> 4, lo = lane & 15;
  const int wave = threadIdx.x >> 6, wm = (wave & 1) << 6, wn = (wave >> 1) << 6;
#pragma unroll
  for (int nf = 0; nf < 4; ++nf) {
    int gn = n0 + wn + nf * 16 + lo;   // permuted col: n = 4j + g
    int j = gn >> 2, g = gn & 3;
    float bias = (j < H) ? bvec[g * H + j] : 0.f;
#pragma unroll
    for (int mf = 0; mf < 4; ++mf)
#pragma unroll
      for (int r = 0; r < 4; ++r) {
        float zs = acc[mf][nf][r] + bias;        // gate g
        float v1 = __shfl_xor(zs, 1);            // gate g^1
        float v2 = __shfl_xor(zs, 2);            // gate g^2
        float v3 = __shfl_xor(v1, 2);            // gate g^3
        if (g == r && j < H) {
          // pick(q): value for gate q is at t=q^g in {zs,v1,v2,v3}
          float zi, zf, zo, zu;
          { int t = 0 ^ g; zi = t == 0 ? zs : t == 1 ? v1 : t == 2 ? v2 : v3; }
          { int t = 1 ^ g; zf = t == 0 ? zs : t == 1 ? v1 : t == 2 ? v2 : v3; }
          { int t = 2 ^ g; zo = t == 0 ? zs : t == 1 ? v1 : t == 2 ? v2 : v3; }
          { int t = 3 ^ g; zu = t == 0 ? zs : t == 1 ? v1 : t == 2 ? v2 : v3; }
          float iv = 1.f / (1.f + __expf(-zi));
          float fv = 1.f / (1.f + __expf(-zf));
          float ov = 1.f / (1.f + __expf(-zo));
          float uv = tanhf(zu);
          int row = m0 + wm + mf * 16 + quad * 4 + r;
          size_t oidx = (size_t)row * H + j;
          float cp = c_prev[oidx];
          float cv = fv * cp + iv * uv;
          hout[oidx] = ov * tanhf(cv);
          cout[oidx] = cv;
        }
      }
  }
}

extern "C" void kernel_launch(void* const* d_in, const int* in_sizes, int n_in,
                              void* d_out, int out_size, void* d_ws, size_t ws_size,
                              hipStream_t stream) {
  const float* inputs = (const float*)d_in[0];
  const float* c_prev = (const float*)d_in[1];
  const float* h_prev = (const float*)d_in[2];
  const float* wx  = (const float*)d_in[3];
  const float* wh  = (const float*)d_in[4];
  const float* wmx = (const float*)d_in[5];
  const float* wmh = (const float*)d_in[6];
  const float* bv  = (const float*)d_in[7];
  const float* gx  = (const float*)d_in[8];
  const float* gh  = (const float*)d_in[9];
  const float* gmx = (const float*)d_in[10];
  const float* gmh = (const float*)d_in[11];

  char* ws = (char*)d_ws;
  float* s_wx  = (float*)(ws + OFF_SWX);
  float* s_wh  = (float*)(ws + OFF_SWH);
  float* s_wmx = (float*)(ws + OFF_SWMX);
  float* s_wmh = (float*)(ws + OFF_SWMH);
  float* wmxn  = (float*)(ws + OFF_WMXN);
  float* parts = (float*)(ws + OFF_PART);
  ushort_t* hbf   = (ushort_t*)(ws + OFF_HBF);
  ushort_t* m_ext = (ushort_t*)(ws + OFF_MEXT);
  ushort_t* wmhT  = (ushort_t*)(ws + OFF_WMHT);
  ushort_t* whxT  = (ushort_t*)(ws + OFF_WHXT);

  float* hout = (float*)d_out;
  float* cout = hout + (size_t)BATCH * H;

  colsum_partial_kernel<<<dim3(30, 4, 8), 256, 0, stream>>>(wx, wh, wmx, wmh, parts);
  scales_final_kernel<<<dim3(30, 4), 256, 0, stream>>>(parts, gx, gh, gmx, gmh,
                                                       s_wx, s_wh, s_wmx, s_wmh);
  cvt_h_kernel<<<62464, 256, 0, stream>>>(h_prev, hbf);
  wmxn_kernel<<<75, 256, 0, stream>>>(wmx, s_wmx, wmxn);
  wmhT_kernel<<<dim3(60, 61), 256, 0, stream>>>(wmh, s_wmh, wmhT);
  whxT_kernel<<<dim3(238, 61), 256, 0, stream>>>(wh, wx, s_wh, s_wx, whxT);
  mext_tail_kernel<<<1024, 256, 0, stream>>>(inputs, m_ext);
  whxT_tail_kernel<<<610, 256, 0, stream>>>(whxT);
  gemmA_kernel<<<dim3(64, 15), 256, 0, stream>>>(hbf, wmhT, inputs, wmxn, m_ext);
  gemmB_kernel<<<dim3(64, 60), 256, 0, stream>>>(m_ext, whxT, bv, c_prev, hout, cout);
}

// Round 2
// 1086.351 us; speedup vs baseline: 1.0102x; 1.0102x over previous
//
#include <hip/hip_runtime.h>

typedef unsigned short ushort_t;
typedef short bf16x8 __attribute__((ext_vector_type(8)));
typedef float f32x4 __attribute__((ext_vector_type(4)));

#define H 1900
#define FH 7600      // 4*H
#define BATCH 8192
#define KP 1952      // padded K stride: 1900 m | 20 pad | 10 inputs | 22 pad (mult of 32)
#define NP_A 1920    // padded N for gemmA (m columns)
#define NB 7680      // padded row count of whxT
#define BK 32
#define KITERS (KP / BK)   // 61

// ---- ws layout (bytes) ----
static const size_t OFF_SWX  = 0;          // 7600 f32
static const size_t OFF_SWH  = 32768;      // 7600 f32
static const size_t OFF_SWMX = 65536;      // 1900 f32
static const size_t OFF_SWMH = 73728;      // 1900 f32
static const size_t OFF_WMXN = 81920;      // 10*1920 f32 (pre-scaled wmx_n)
static const size_t OFF_PART = 163840;     // partial colsums: 8*(7600+7600+1900+1900) f32
static const size_t OFF_HBF  = 786432;                   // h_prev bf16 [8192][1952]
static const size_t OFF_MEXT = OFF_HBF + 31981568;       // m_ext bf16 [8192][1952]
static const size_t OFF_WMHT = OFF_MEXT + 31981568;      // wmh_n^T bf16 [1920][1952]
static const size_t OFF_WHXT = OFF_WMHT + 7495680;       // [wh_n|wx_n]^T perm bf16 [7680][1952]
// end = OFF_WHXT + 29982720 ≈ 97.5 MB

// partial-sum sub-offsets (in floats, within OFF_PART)
#define PW_X  0
#define PW_H  60800
#define PW_MX 121600
#define PW_MH 136800

__device__ __forceinline__ ushort_t f2bf(float x) {
  unsigned u = __float_as_uint(x);
  return (ushort_t)((u + 0x7fffu + ((u >> 16) & 1u)) >> 16);
}

// async global->LDS, 16 B per lane; LDS dest = base + lane*16 (wave-uniform base)
__device__ __forceinline__ void gl_lds16(const ushort_t* g, ushort_t* lds) {
  __builtin_amdgcn_global_load_lds(
      (const __attribute__((address_space(1))) unsigned int*)(g),
      (__attribute__((address_space(3))) unsigned int*)(lds), 16, 0, 0);
}

// ---------------- scales: per-column l2-norm partials, then gain*rsqrt ----------------
__global__ void colsum_partial_kernel(const float* __restrict__ wx, const float* __restrict__ wh,
                                      const float* __restrict__ wmx, const float* __restrict__ wmh,
                                      float* __restrict__ parts) {
  int c = blockIdx.x * 256 + threadIdx.x;
  int y = blockIdx.y, p = blockIdx.z;
  const float* W; int K, N; float* out;
  if (y == 0)      { W = wx;  K = 10;   N = FH; out = parts + PW_X  + (size_t)p * FH; }
  else if (y == 1) { W = wh;  K = 1900; N = FH; out = parts + PW_H  + (size_t)p * FH; }
  else if (y == 2) { W = wmx; K = 10;   N = H;  out = parts + PW_MX + (size_t)p * H;  }
  else             { W = wmh; K = 1900; N = H;  out = parts + PW_MH + (size_t)p * H;  }
  if (c >= N) return;
  int rp = (K + 7) / 8;
  int r0 = p * rp, r1 = r0 + rp; if (r1 > K) r1 = K;
  float s = 0.f;
  for (int r = r0; r < r1; ++r) { float v = W[(size_t)r * N + c]; s += v * v; }
  out[c] = s;
}

__global__ void scales_final_kernel(const float* __restrict__ parts,
                                    const float* __restrict__ gx, const float* __restrict__ gh,
                                    const float* __restrict__ gmx, const float* __restrict__ gmh,
                                    float* __restrict__ s_wx, float* __restrict__ s_wh,
                                    float* __restrict__ s_wmx, float* __restrict__ s_wmh) {
  int c = blockIdx.x * 256 + threadIdx.x;
  int y = blockIdx.y;
  const float* pp; int N; const float* g; float* out;
  if (y == 0)      { pp = parts + PW_X;  N = FH; g = gx;  out = s_wx;  }
  else if (y == 1) { pp = parts + PW_H;  N = FH; g = gh;  out = s_wh;  }
  else if (y == 2) { pp = parts + PW_MX; N = H;  g = gmx; out = s_wmx; }
  else             { pp = parts + PW_MH; N = H;  g = gmh; out = s_wmh; }
  if (c >= N) return;
  float s = 0.f;
  for (int p = 0; p < 8; ++p) s += pp[(size_t)p * N + c];
  out[c] = g[c] * rsqrtf(fmaxf(s, 1e-12f));
}

// ---------------- conversions ----------------
__global__ void cvt_h_kernel(const float* __restrict__ h_prev, ushort_t* __restrict__ hbf) {
  size_t idx = (size_t)blockIdx.x * 256 + threadIdx.x;   // < 8192*1952
  int row = (int)(idx / KP), col = (int)(idx % KP);
  float v = (col < H) ? h_prev[(size_t)row * H + col] : 0.f;
  hbf[idx] = f2bf(v);
}

__global__ void wmxn_kernel(const float* __restrict__ wmx, const float* __restrict__ s_wmx,
                            float* __restrict__ wmxn) {
  int idx = blockIdx.x * 256 + threadIdx.x;  // < 19200
  int i = idx / NP_A, j = idx - i * NP_A;
  wmxn[idx] = (j < H) ? wmx[i * H + j] * s_wmx[j] : 0.f;
}

// wmh [1900][1900] -> wmhT [1920][1952] bf16, transposed, pre-scaled
__global__ void wmhT_kernel(const float* __restrict__ wmh, const float* __restrict__ s_wmh,
                            ushort_t* __restrict__ wmhT) {
  __shared__ float tile[32][33];
  int n0 = blockIdx.x * 32, k0 = blockIdx.y * 32;
  int tx = threadIdx.x & 31, ty = threadIdx.x >> 5;   // ty 0..7
#pragma unroll
  for (int it = 0; it < 4; ++it) {
    int k = k0 + ty + it * 8, n = n0 + tx;
    float v = (k < H && n < H) ? wmh[(size_t)k * H + n] : 0.f;
    tile[ty + it * 8][tx] = v;   // tile[k_local][n_local]
  }
  __syncthreads();
#pragma unroll
  for (int it = 0; it < 4; ++it) {
    int n = n0 + ty + it * 8, k = k0 + tx;
    float v = tile[tx][ty + it * 8];
    float s = (n < H) ? s_wmh[n] : 0.f;
    wmhT[(size_t)n * KP + k] = f2bf(v * s);
  }
}

// wh [1900][7600] + wx [10][7600] -> whxT [7680][1952]: row n=4j+g <- col c=g*1900+j,
// k<1900: wh_n ; 1920<=k<1930: wx_n ; else 0. Pre-scaled.
__global__ void whxT_kernel(const float* __restrict__ wh, const float* __restrict__ wx,
                            const float* __restrict__ s_wh, const float* __restrict__ s_wx,
                            ushort_t* __restrict__ whxT) {
  __shared__ float tile[32][33];
  int c0 = blockIdx.x * 32, k0 = blockIdx.y * 32;
  int tx = threadIdx.x & 31, ty = threadIdx.x >> 5;
#pragma unroll
  for (int it = 0; it < 4; ++it) {
    int k = k0 + ty + it * 8, c = c0 + tx;
    float v = 0.f;
    if (c < FH) {
      if (k < H) v = wh[(size_t)k * FH + c] * s_wh[c];
      else if (k >= NP_A && k < NP_A + 10) v = wx[(size_t)(k - NP_A) * FH + c] * s_wx[c];
    }
    tile[ty + it * 8][tx] = v;   // tile[k_local][c_local]
  }
  __syncthreads();
#pragma unroll
  for (int it = 0; it < 4; ++it) {
    int c = c0 + ty + it * 8, k = k0 + tx;
    if (c < FH) {
      int g = c / H; int j = c - g * H; int n = 4 * j + g;
      whxT[(size_t)n * KP + k] = f2bf(tile[tx][ty + it * 8]);
    }
  }
}

__global__ void mext_tail_kernel(const float* __restrict__ inputs, ushort_t* __restrict__ m_ext) {
  int idx = blockIdx.x * 256 + threadIdx.x;   // < 8192*32
  int row = idx >> 5, c = idx & 31;
  float v = (c < 10) ? inputs[(size_t)row * 10 + c] : 0.f;
  m_ext[(size_t)row * KP + NP_A + c] = f2bf(v);
}

__global__ void whxT_tail_kernel(ushort_t* __restrict__ whxT) {
  int idx = blockIdx.x * 256 + threadIdx.x;   // < 80*1952
  whxT[(size_t)FH * KP + idx] = 0;
}

// ---------------- GEMM core: 128x128 tile, BK=32, NT, 16x16x32 bf16 MFMA ----------------
// LDS tile layout [128 rows][32 elems], 16B "halves" XOR-swizzled:
//   LDS slot (row, h_lds) holds global half h_g = h_lds ^ ((row>>1)&3)
// Staging via global_load_lds width-16: lane i of a wave-chunk (16 rows) covers
//   row = R + (i>>2), h_lds = i&3  ->  loads global half (i&3) ^ ((i>>3)&3).
__device__ __forceinline__ void gemm_tile(const ushort_t* __restrict__ Ag,
                                          const ushort_t* __restrict__ Bg,
                                          int m0, int n0,
                                          ushort_t* As, ushort_t* Bs,
                                          f32x4 acc[4][4]) {
  const int tid = threadIdx.x;
  const int lane = tid & 63;
  const int quad = lane >> 4;
  const int lo = lane & 15;
  const int wave = tid >> 6;
  const int wm = (wave & 1) << 6;
  const int wn = (wave >> 1) << 6;
  const int sw = (lo >> 1) & 3;                       // read-side swizzle key

  // staging assignment: wave w loads rows [16w,16w+16) and [64+16w, 64+16w+16) of A and B
  const int cr = lane >> 2;                           // chunk-row 0..15
  const int hg = (lane & 3) ^ ((lane >> 3) & 3);      // swizzled global half 0..3
  const int r0 = wave * 16 + cr;
  const int r1 = 64 + wave * 16 + cr;
  const ushort_t* gA0 = Ag + (size_t)(m0 + r0) * KP + hg * 8;
  const ushort_t* gA1 = Ag + (size_t)(m0 + r1) * KP + hg * 8;
  const ushort_t* gB0 = Bg + (size_t)(n0 + r0) * KP + hg * 8;
  const ushort_t* gB1 = Bg + (size_t)(n0 + r1) * KP + hg * 8;
  ushort_t* lA0 = As + (wave * 16) * BK;              // wave-uniform LDS bases
  ushort_t* lA1 = As + (64 + wave * 16) * BK;
  ushort_t* lB0 = Bs + (wave * 16) * BK;
  ushort_t* lB1 = Bs + (64 + wave * 16) * BK;

  for (int kt = 0; kt < KITERS; ++kt) {
    __syncthreads();   // prev iter's LDS reads complete before DMA overwrites
    gl_lds16(gA0, lA0);
    gl_lds16(gA1, lA1);
    gl_lds16(gB0, lB0);
    gl_lds16(gB1, lB1);
    __syncthreads();   // drains vmcnt(0): LDS tile populated by all waves
    bf16x8 af[4], bfv[4];
#pragma unroll
    for (int mf = 0; mf < 4; ++mf)
      af[mf] = *(const bf16x8*)(As + (wm + mf * 16 + lo) * BK + ((quad ^ sw) << 3));
#pragma unroll
    for (int nf = 0; nf < 4; ++nf)
      bfv[nf] = *(const bf16x8*)(Bs + (wn + nf * 16 + lo) * BK + ((quad ^ sw) << 3));
#pragma unroll
    for (int mf = 0; mf < 4; ++mf)
#pragma unroll
      for (int nf = 0; nf < 4; ++nf)
        acc[mf][nf] = __builtin_amdgcn_mfma_f32_16x16x32_bf16(af[mf], bfv[nf], acc[mf][nf], 0, 0, 0);
    gA0 += BK; gA1 += BK; gB0 += BK; gB1 += BK;
  }
}

// GEMM-A: P = h_prev_bf @ wmh_n^T ; epilogue m = (inputs·wmx_n) * P -> m_ext bf16
__global__ void __launch_bounds__(256) gemmA_kernel(const ushort_t* __restrict__ hbf,
                                                    const ushort_t* __restrict__ wmhT,
                                                    const float* __restrict__ inputs,
                                                    const float* __restrict__ wmxn,
                                                    ushort_t* __restrict__ m_ext) {
  __shared__ __align__(16) char smem[16384];
  ushort_t* As = (ushort_t*)smem;
  ushort_t* Bs = (ushort_t*)(smem + 8192);
  f32x4 acc[4][4];
  f32x4 zv = {0.f, 0.f, 0.f, 0.f};
#pragma unroll
  for (int a = 0; a < 4; ++a)
#pragma unroll
    for (int bq = 0; bq < 4; ++bq) acc[a][bq] = zv;
  int m0 = blockIdx.x * 128, n0 = blockIdx.y * 128;
  gemm_tile(hbf, wmhT, m0, n0, As, Bs, acc);
  __syncthreads();
  float* inL  = (float*)smem;            // [128][10]
  float* wmxL = (float*)(smem + 5120);   // [10][128]
  for (int t = threadIdx.x; t < 1280; t += 256) {
    int r = t / 10, i = t - r * 10;
    inL[t] = inputs[(size_t)(m0 + r) * 10 + i];
  }
  for (int t = threadIdx.x; t < 1280; t += 256) {
    int i = t >> 7, c = t & 127;
    wmxL[t] = wmxn[i * NP_A + n0 + c];
  }
  __syncthreads();
  const int lane = threadIdx.x & 63, quad = lane >> 4, lo = lane & 15;
  const int wave = threadIdx.x >> 6, wm = (wave & 1) << 6, wn = (wave >> 1) << 6;
#pragma unroll
  for (int mf = 0; mf < 4; ++mf)
#pragma unroll
    for (int r = 0; r < 4; ++r) {
      int rl = wm + mf * 16 + quad * 4 + r;
      float inrow[10];
#pragma unroll
      for (int i = 0; i < 10; ++i) inrow[i] = inL[rl * 10 + i];
#pragma unroll
      for (int nf = 0; nf < 4; ++nf) {
        int cl = wn + nf * 16 + lo;
        float mx = 0.f;
#pragma unroll
        for (int i = 0; i < 10; ++i) mx += inrow[i] * wmxL[i * 128 + cl];
        float mv = acc[mf][nf][r] * mx;
        m_ext[(size_t)(m0 + rl) * KP + (n0 + cl)] = f2bf(mv);
      }
    }
}

// GEMM-B: z = m_ext @ whxT^T (+bias) ; epilogue: gates via shfl butterfly -> h, c
__global__ void __launch_bounds__(256) gemmB_kernel(const ushort_t* __restrict__ mext,
                                                    const ushort_t* __restrict__ whxT,
                                                    const float* __restrict__ bvec,
                                                    const float* __restrict__ c_prev,
                                                    float* __restrict__ hout,
                                                    float* __restrict__ cout) {
  __shared__ __align__(16) char smem[16384];
  ushort_t* As = (ushort_t*)smem;
  ushort_t* Bs = (ushort_t*)(smem + 8192);
  f32x4 acc[4][4];
  f32x4 zv = {0.f, 0.f, 0.f, 0.f};
#pragma unroll
  for (int a = 0; a < 4; ++a)
#pragma unroll
    for (int bq = 0; bq < 4; ++bq) acc[a][bq] = zv;
  int m0 = blockIdx.x * 128, n0 = blockIdx.y * 128;
  gemm_tile(mext, whxT, m0, n0, As, Bs, acc);
  const int lane = threadIdx.x & 63, quad = lane >> 4, lo = lane & 15;
  const int wave = threadIdx.x >> 6, wm = (wave & 1) << 6, wn = (wave >> 1) << 6;
#pragma unroll
  for (int nf = 0; nf < 4; ++nf) {
    int gn = n0 + wn + nf * 16 + lo;   // permuted col: n = 4j + g
    int j = gn >> 2, g = gn & 3;
    float bias = (j < H) ? bvec[g * H + j] : 0.f;
#pragma unroll
    for (int mf = 0; mf < 4; ++mf)
#pragma unroll
      for (int r = 0; r < 4; ++r) {
        float zs = acc[mf][nf][r] + bias;        // gate g
        float v1 = __shfl_xor(zs, 1);            // gate g^1
        float v2 = __shfl_xor(zs, 2);            // gate g^2
        float v3 = __shfl_xor(v1, 2);            // gate g^3
        if (g == r && j < H) {
          // pick(q): value for gate q is at t=q^g in {zs,v1,v2,v3}
          float zi, zf, zo, zu;
          { int t = 0 ^ g; zi = t == 0 ? zs : t == 1 ? v1 : t == 2 ? v2 : v3; }
          { int t = 1 ^ g; zf = t == 0 ? zs : t == 1 ? v1 : t == 2 ? v2 : v3; }
          { int t = 2 ^ g; zo = t == 0 ? zs : t == 1 ? v1 : t == 2 ? v2 : v3; }
          { int t = 3 ^ g; zu = t == 0 ? zs : t == 1 ? v1 : t == 2 ? v2 : v3; }
          float iv = 1.f / (1.f + __expf(-zi));
          float fv = 1.f / (1.f + __expf(-zf));
          float ov = 1.f / (1.f + __expf(-zo));
          float uv = tanhf(zu);
          int row = m0 + wm + mf * 16 + quad * 4 + r;
          size_t oidx = (size_t)row * H + j;
          float cp = c_prev[oidx];
          float cv = fv * cp + iv * uv;
          hout[oidx] = ov * tanhf(cv);
          cout[oidx] = cv;
        }
      }
  }
}

extern "C" void kernel_launch(void* const* d_in, const int* in_sizes, int n_in,
                              void* d_out, int out_size, void* d_ws, size_t ws_size,
                              hipStream_t stream) {
  const float* inputs = (const float*)d_in[0];
  const float* c_prev = (const float*)d_in[1];
  const float* h_prev = (const float*)d_in[2];
  const float* wx  = (const float*)d_in[3];
  const float* wh  = (const float*)d_in[4];
  const float* wmx = (const float*)d_in[5];
  const float* wmh = (const float*)d_in[6];
  const float* bv  = (const float*)d_in[7];
  const float* gx  = (const float*)d_in[8];
  const float* gh  = (const float*)d_in[9];
  const float* gmx = (const float*)d_in[10];
  const float* gmh = (const float*)d_in[11];

  char* ws = (char*)d_ws;
  float* s_wx  = (float*)(ws + OFF_SWX);
  float* s_wh  = (float*)(ws + OFF_SWH);
  float* s_wmx = (float*)(ws + OFF_SWMX);
  float* s_wmh = (float*)(ws + OFF_SWMH);
  float* wmxn  = (float*)(ws + OFF_WMXN);
  float* parts = (float*)(ws + OFF_PART);
  ushort_t* hbf   = (ushort_t*)(ws + OFF_HBF);
  ushort_t* m_ext = (ushort_t*)(ws + OFF_MEXT);
  ushort_t* wmhT  = (ushort_t*)(ws + OFF_WMHT);
  ushort_t* whxT  = (ushort_t*)(ws + OFF_WHXT);

  float* hout = (float*)d_out;
  float* cout = hout + (size_t)BATCH * H;

  colsum_partial_kernel<<<dim3(30, 4, 8), 256, 0, stream>>>(wx, wh, wmx, wmh, parts);
  scales_final_kernel<<<dim3(30, 4), 256, 0, stream>>>(parts, gx, gh, gmx, gmh,
                                                       s_wx, s_wh, s_wmx, s_wmh);
  cvt_h_kernel<<<62464, 256, 0, stream>>>(h_prev, hbf);
  wmxn_kernel<<<75, 256, 0, stream>>>(wmx, s_wmx, wmxn);
  wmhT_kernel<<<dim3(60, 61), 256, 0, stream>>>(wmh, s_wmh, wmhT);
  whxT_kernel<<<dim3(238, 61), 256, 0, stream>>>(wh, wx, s_wh, s_wx, whxT);
  mext_tail_kernel<<<1024, 256, 0, stream>>>(inputs, m_ext);
  whxT_tail_kernel<<<610, 256, 0, stream>>>(whxT);
  gemmA_kernel<<<dim3(64, 15), 256, 0, stream>>>(hbf, wmhT, inputs, wmxn, m_ext);
  gemmB_kernel<<<dim3(64, 60), 256, 0, stream>>>(m_ext, whxT, bv, c_prev, hout, cout);
}